// Round 2
// baseline (467.646 us; speedup 1.0000x reference)
//
#include <hip/hip_runtime.h>

typedef unsigned short ushort_t;
typedef short s16x8 __attribute__((ext_vector_type(8)));
typedef float f32x4 __attribute__((ext_vector_type(4)));
typedef unsigned short u16x4 __attribute__((ext_vector_type(4)));

#define KDIM 256
#define BK 64
#define BM 128
#define BN 128
#define LDST 72          // 64 + 8 pad (bf16 elems); row = 144B -> 2-way bank alias (free)
#define LV_TOTAL 21760
#define NQ 8000          // BS*LQ

__device__ inline unsigned short f2b(float f) {
  union { float f; unsigned u; } v; v.f = f;
  return (unsigned short)((v.u + 0x7fffu + ((v.u >> 16) & 1u)) >> 16);  // RNE
}
__device__ inline float b2f(unsigned short h) {
  union { unsigned u; float f; } v; v.u = ((unsigned)h) << 16;
  return v.f;
}

// ---- weight prep: transpose to [n][k] + bf16 convert (re-done every launch; ws is re-poisoned) ----
__global__ __launch_bounds__(256) void prep_weights(
    const float* __restrict__ w_off, const float* __restrict__ w_attn,
    const float* __restrict__ w_val, const float* __restrict__ w_out,
    const float* __restrict__ b_off, const float* __restrict__ b_attn,
    ushort_t* __restrict__ wt_val, ushort_t* __restrict__ wt_qoa,
    ushort_t* __restrict__ wt_out, float* __restrict__ bias_qoa)
{
  int bid = blockIdx.x;
  int k = threadIdx.x;
  if (bid < 256) {
    int n = bid;
    wt_val[n*KDIM + k] = f2b(w_val[k*256 + n]);
  } else if (bid < 640) {
    int n = bid - 256;
    float v = (n < 256) ? w_off[k*256 + n] : w_attn[k*128 + (n - 256)];
    wt_qoa[n*KDIM + k] = f2b(v);
  } else if (bid < 896) {
    int n = bid - 640;
    wt_out[n*KDIM + k] = f2b(w_out[k*256 + n]);
  } else {
    for (int i = k; i < 384; i += 256)
      bias_qoa[i] = (i < 256) ? b_off[i] : b_attn[i - 256];
  }
}

// ---- generic MFMA GEMM: C[M,N] = A[M,256](fp32->bf16) * Bt[N,256](bf16)^T + bias ----
// block tile 128x128, BK=64, 4 waves: wave w -> rows [32w,32w+32), all 128 cols
__global__ __launch_bounds__(256) void gemm_bf16(
    const float* __restrict__ A, const ushort_t* __restrict__ Bt,
    const float* __restrict__ bias, float* __restrict__ Cf,
    ushort_t* __restrict__ Cb, int M, int N)
{
  __shared__ ushort_t sA[BM * LDST];
  __shared__ ushort_t sB[BN * LDST];
  const int tid  = threadIdx.x;
  const int m0   = blockIdx.x * BM;
  const int n0   = blockIdx.y * BN;
  const int wave = tid >> 6;
  const int lane = tid & 63;
  const int lrow = lane & 15;
  const int quad = lane >> 4;

  f32x4 acc[2][8];
  #pragma unroll
  for (int i = 0; i < 2; ++i)
    #pragma unroll
    for (int j = 0; j < 8; ++j) acc[i][j] = {0.f, 0.f, 0.f, 0.f};

  for (int kc = 0; kc < KDIM; kc += BK) {
    // stage A: 128x64 fp32 -> bf16 LDS (coalesced float4 loads)
    #pragma unroll
    for (int i = 0; i < 8; ++i) {
      int f   = tid + i * 256;   // float4 index; 16 per row
      int row = f >> 4;
      int c4  = f & 15;
      int gr  = m0 + row;
      float4 val = {0.f, 0.f, 0.f, 0.f};
      if (gr < M) val = *(const float4*)(A + (size_t)gr * KDIM + kc + c4 * 4);
      u16x4 t;
      t.x = f2b(val.x); t.y = f2b(val.y); t.z = f2b(val.z); t.w = f2b(val.w);
      *(u16x4*)&sA[row * LDST + c4 * 4] = t;
    }
    // stage B: 128x64 bf16 (pre-transposed [n][k]) -> straight vector copy
    #pragma unroll
    for (int i = 0; i < 4; ++i) {
      int f   = tid + i * 256;   // 16B-chunk index; 8 per row
      int row = f >> 3;
      int seg = f & 7;
      s16x8 v = *(const s16x8*)(Bt + (size_t)(n0 + row) * KDIM + kc + seg * 8);
      *(s16x8*)&sB[row * LDST + seg * 8] = v;
    }
    __syncthreads();
    #pragma unroll
    for (int ki = 0; ki < BK; ki += 32) {
      int krow = ki + quad * 8;
      s16x8 af[2], bfr[8];
      #pragma unroll
      for (int mt = 0; mt < 2; ++mt)
        af[mt] = *(const s16x8*)&sA[(wave * 32 + mt * 16 + lrow) * LDST + krow];
      #pragma unroll
      for (int nt = 0; nt < 8; ++nt)
        bfr[nt] = *(const s16x8*)&sB[(nt * 16 + lrow) * LDST + krow];
      #pragma unroll
      for (int mt = 0; mt < 2; ++mt)
        #pragma unroll
        for (int nt = 0; nt < 8; ++nt)
          acc[mt][nt] = __builtin_amdgcn_mfma_f32_16x16x32_bf16(
              af[mt], bfr[nt], acc[mt][nt], 0, 0, 0);
    }
    __syncthreads();
  }
  // epilogue: D row = quad*4 + reg, col = lane&15 (verified layout)
  #pragma unroll
  for (int mt = 0; mt < 2; ++mt) {
    int gmb = m0 + wave * 32 + mt * 16 + quad * 4;
    #pragma unroll
    for (int nt = 0; nt < 8; ++nt) {
      int gn = n0 + nt * 16 + lrow;
      float bv = bias[gn];
      #pragma unroll
      for (int r = 0; r < 4; ++r) {
        int gm = gmb + r;
        if (gm < M) {
          float val = acc[mt][nt][r] + bv;
          if (Cb) Cb[(size_t)gm * N + gn] = f2b(val);
          else    Cf[(size_t)gm * N + gn] = val;
        }
      }
    }
  }
}

// ---- fused softmax + location + bilinear sampling + attention-weighted sum ----
// one block per (b,q); phase1: 128 threads = (h,p) pairs; phase2: 256 threads = (h,d)
__global__ __launch_bounds__(256) void ms_deform_sample(
    const ushort_t* __restrict__ v,     // [BS][21760][256] bf16
    const float* __restrict__ qoa,      // [8000][384]: 0..255 off, 256..383 attn logits
    const float* __restrict__ refp,     // [8000][4]
    float* __restrict__ outq)           // [8000][256]
{
  __shared__ float s_w[128 * 4];
  __shared__ int   s_i[128 * 4];
  const int bq  = blockIdx.x;
  const int b   = bq / 1000;
  const int tid = threadIdx.x;

  if (tid < 128) {
    const int p = tid & 15;
    const float* qrow = qoa + (size_t)bq * 384;
    // softmax over 16 points per head (16-lane groups, wave-aligned)
    float logit = qrow[256 + tid];
    float mx = logit;
    #pragma unroll
    for (int s = 8; s >= 1; s >>= 1) mx = fmaxf(mx, __shfl_xor(mx, s, 16));
    float e = __expf(logit - mx);
    float sum = e;
    #pragma unroll
    for (int s = 8; s >= 1; s >>= 1) sum += __shfl_xor(sum, s, 16);
    float aw = e / sum;

    float ox = qrow[tid * 2], oy = qrow[tid * 2 + 1];
    const float* rp = refp + (size_t)bq * 4;
    float rx = rp[0], ry = rp[1], rw = rp[2], rh = rp[3];
    const int lvl = p >> 2;
    const int HWs[4] = {128, 64, 32, 16};
    const int STs[4] = {0, 16384, 20480, 21504};
    int W = HWs[lvl], H = HWs[lvl], st = STs[lvl];
    // loc = ref + off * (1/4) * ref_wh * 0.5
    float lx = rx + ox * 0.125f * rw;
    float ly = ry + oy * 0.125f * rh;
    float x = lx * (float)W - 0.5f;
    float y = ly * (float)H - 0.5f;
    float x0f = floorf(x), y0f = floorf(y);
    int x0 = (int)x0f, y0 = (int)y0f;
    float fx = x - x0f, fy = y - y0f;
    float wc[4] = {(1.f - fx) * (1.f - fy), fx * (1.f - fy),
                   (1.f - fx) * fy,         fx * fy};
    #pragma unroll
    for (int c = 0; c < 4; ++c) {
      int xi = x0 + (c & 1);
      int yi = y0 + (c >> 1);
      bool valid = (xi >= 0) && (xi < W) && (yi >= 0) && (yi < H);
      int xc = min(max(xi, 0), W - 1);
      int yc = min(max(yi, 0), H - 1);
      s_w[tid * 4 + c] = valid ? wc[c] * aw : 0.f;
      s_i[tid * 4 + c] = st + yc * W + xc;
    }
  }
  __syncthreads();

  const int h = tid >> 5, d = tid & 31;
  const ushort_t* vb = v + (size_t)b * LV_TOTAL * 256 + h * 32 + d;
  float acc = 0.f;
  #pragma unroll
  for (int p = 0; p < 16; ++p) {
    int j = (h * 16 + p) * 4;
    #pragma unroll
    for (int c = 0; c < 4; ++c) {
      acc += s_w[j + c] * b2f(vb[(size_t)s_i[j + c] * 256]);
    }
  }
  outq[(size_t)bq * 256 + tid] = acc;
}

extern "C" void kernel_launch(void* const* d_in, const int* in_sizes, int n_in,
                              void* d_out, int out_size, void* d_ws, size_t ws_size,
                              hipStream_t stream) {
  const float* query  = (const float*)d_in[0];
  const float* refp   = (const float*)d_in[1];
  const float* value  = (const float*)d_in[2];
  // d_in[3] spatial_shapes: compile-time constants
  const float* w_off  = (const float*)d_in[4];
  const float* b_off  = (const float*)d_in[5];
  const float* w_attn = (const float*)d_in[6];
  const float* b_attn = (const float*)d_in[7];
  const float* w_val  = (const float*)d_in[8];
  const float* b_val  = (const float*)d_in[9];
  const float* w_out  = (const float*)d_in[10];
  const float* b_out  = (const float*)d_in[11];
  float* out = (float*)d_out;

  char* ws = (char*)d_ws;
  // ws layout (all 16B-aligned): total 110,069,760 B
  const size_t WS_NEEDED = 110069760;
  if (ws_size < WS_NEEDED) return;  // clean correctness failure instead of OOB scribble
  ushort_t* wt_val   = (ushort_t*)(ws);                 // 256*256*2  = 131072
  ushort_t* wt_qoa   = (ushort_t*)(ws + 131072);        // 384*256*2  = 196608
  ushort_t* wt_out   = (ushort_t*)(ws + 327680);        // 256*256*2  = 131072
  float*    bias_qoa = (float*)   (ws + 458752);        // 384*4 -> pad 2048
  ushort_t* v_proj   = (ushort_t*)(ws + 460800);        // 174080*256*2 = 89128960
  float*    qoa      = (float*)   (ws + 89589760);      // 8000*384*4 = 12288000
  float*    outq     = (float*)   (ws + 101877760);     // 8000*256*4 = 8192000

  prep_weights<<<897, 256, 0, stream>>>(w_off, w_attn, w_val, w_out, b_off, b_attn,
                                        wt_val, wt_qoa, wt_out, bias_qoa);
  // value projection: [174080,256] x [256,256] -> bf16 v_proj
  gemm_bf16<<<dim3(1360, 2), 256, 0, stream>>>(value, wt_val, b_val,
                                               nullptr, v_proj, 174080, 256);
  // query -> offsets|attn logits: [8000,256] x [256,384] -> fp32
  gemm_bf16<<<dim3(63, 3), 256, 0, stream>>>(query, wt_qoa, bias_qoa,
                                             qoa, nullptr, NQ, 384);
  // sampling + softmax + weighted sum
  ms_deform_sample<<<NQ, 256, 0, stream>>>(v_proj, qoa, refp, outq);
  // output projection: [8000,256] x [256,256] -> d_out fp32
  gemm_bf16<<<dim3(63, 2), 256, 0, stream>>>(outq, wt_out, b_out,
                                             out, nullptr, NQ, 256);
}